// Round 4
// baseline (187.288 us; speedup 1.0000x reference)
//
#include <hip/hip_runtime.h>
#include <math.h>

#define HH 512
#define FF 2048
#define BB 16
#define SS 2048
#define MM 32768  // BB*SS

using f32x4 = __attribute__((ext_vector_type(4))) float;
using s16x8 = __attribute__((ext_vector_type(8))) short;

struct __align__(8)  US4 { unsigned short x, y, z, w; };
struct __align__(16) US8 { unsigned short s[8]; };

__device__ __forceinline__ unsigned short f2bf(float f) {
  unsigned int u = __builtin_bit_cast(unsigned int, f);
  u += 0x7fffu + ((u >> 16) & 1u);
  return (unsigned short)(u >> 16);
}
__device__ __forceinline__ float bf2f(unsigned short u) {
  unsigned int x = ((unsigned int)u) << 16;
  return __builtin_bit_cast(float, x);
}
__device__ __forceinline__ void gload_lds16(const void* g, void* l) {
  __builtin_amdgcn_global_load_lds(
      (const __attribute__((address_space(1))) unsigned int*)g,
      (__attribute__((address_space(3))) unsigned int*)l, 16, 0, 0);
}

// ---- weight conversions (merged) ----
__global__ void k_conv(const float* __restrict__ We, const float* __restrict__ Wa,
                       unsigned short* __restrict__ OWe, unsigned short* __restrict__ OWa) {
  int bid = blockIdx.x, t = threadIdx.x;
  if (bid < 1024) {
    int idx = bid * 256 + t;  // < 262144
    f32x4 x = *(const f32x4*)(We + (size_t)idx * 4);
    US4 p{f2bf(x.x), f2bf(x.y), f2bf(x.z), f2bf(x.w)};
    *(US4*)(OWe + (size_t)idx * 4) = p;
  } else {
    int idx = (bid - 1024) * 256 + t;  // < 65536
    int k = idx >> 7, h4 = idx & 127;
    f32x4 x = *(const f32x4*)(Wa + (size_t)k * 1024 + 512 + h4 * 4);
    US4 p{f2bf(x.x), f2bf(x.y), f2bf(x.z), f2bf(x.w)};
    *(US4*)(OWa + (size_t)idx * 4) = p;
  }
}

// ---- h = hidden[-1] @ Wh.T + bh : one wave per output (b,j) ----
__global__ void k_h(const float* __restrict__ hidden, const float* __restrict__ Wh,
                    const float* __restrict__ bh, float* __restrict__ h_ws) {
  int t = threadIdx.x, lane = t & 63, wid = t >> 6;
  int out = blockIdx.x * 4 + wid;  // < 8192
  int b = out >> 9, j = out & 511;
  const float* hr = hidden + (1) * BB * FF + b * FF;  // hidden[-1]
  const float* wr = Wh + (size_t)j * FF;
  float a = 0.f;
#pragma unroll
  for (int i = 0; i < 8; ++i) {
    int o = i * 256 + lane * 4;
    f32x4 x = *(const f32x4*)(hr + o);
    f32x4 y = *(const f32x4*)(wr + o);
    a += x.x * y.x + x.y * y.y + x.z * y.z + x.w * y.w;
  }
#pragma unroll
  for (int m = 32; m; m >>= 1) a += __shfl_xor(a, m);
  if (lane == 0) h_ws[out] = a + bh[j];
}

// ---- bb[b][k] = ba[k] + h[b] . Wa[k, 0:512] ----
__global__ void k_bb(const float* __restrict__ h_ws, const float* __restrict__ Wa,
                     const float* __restrict__ ba, float* __restrict__ bb_ws) {
  int t = threadIdx.x, lane = t & 63, wid = t >> 6;
  int out = blockIdx.x * 4 + wid;  // < 8192
  int b = out >> 9, k = out & 511;
  const float* hr = h_ws + b * HH;
  const float* wa = Wa + (size_t)k * 1024;
  float a = 0.f;
#pragma unroll
  for (int i = 0; i < 2; ++i) {
    int o = i * 256 + lane * 4;
    f32x4 x = *(const f32x4*)(hr + o);
    f32x4 y = *(const f32x4*)(wa + o);
    a += x.x * y.x + x.y * y.y + x.z * y.z + x.w * y.w;
  }
#pragma unroll
  for (int m = 32; m; m >>= 1) a += __shfl_xor(a, m);
  if (lane == 0) bb_ws[out] = a + ba[k];
}

// ================= fused GEMM1 + GEMM2 + scores =================
// Block: M=64 x N=512 (full N, enc read once). 512 thr / 8 waves, BK=64.
// Double-buffered LDS (144KB): As0|As1 (8KB each) + Bs0|Bs1 (64KB each).
// Counted-vmcnt pipeline: B gload_lds stays in flight across one compute
// phase; A f32 loads 2-deep (~2 phases in flight). Raw s_barrier + manual
// s_waitcnt; issue order pinned by sched_barrier(0) so vmcnt(2) == "all B
// landed, 2 A-loads may fly".
// Epilogue: eo-tile -> swizzled Cs (aliases Bs1) -> global eo store +
// second GEMM E = eo @ Waeb^T (B-frags straight from L2) -> tanh+v-dot
// -> block-reduced scores sp[m0..m0+63].

template<int CUR, bool IB, bool IA, int WN>
__device__ __forceinline__ void gstep(const float* enc_m0, const unsigned short* Web,
                                      unsigned short* smem, int kt, int t, int lane, int wid,
                                      f32x4* regC, f32x4* regN, f32x4 (&acc)[4][4]) {
  unsigned short* Asc = smem + (CUR ? 4096 : 0);
  unsigned short* Asn = smem + (CUR ? 0 : 4096);
  unsigned short* Bsc = smem + (CUR ? 40960 : 8192);
  unsigned short* Bsn = smem + (CUR ? 8192 : 40960);
  asm volatile("s_waitcnt vmcnt(%0)" :: "i"(WN) : "memory");
  __builtin_amdgcn_sched_barrier(0);
  __builtin_amdgcn_s_barrier();
  if (IB) {
#pragma unroll
    for (int i = 0; i < 8; ++i) {
      int idx = i * 512 + t, row = idx >> 3, c = idx & 7, sc = c ^ (row & 7);
      gload_lds16(Web + (size_t)row * FF + (kt + 64) + sc * 8, Bsn + idx * 8);
    }
  }
  __builtin_amdgcn_sched_barrier(0);
  if (IA) {
#pragma unroll
    for (int i = 0; i < 2; ++i) {
      int idx = i * 512 + t, row = idx >> 4, c4 = idx & 15;
      regN[i] = *(const f32x4*)(enc_m0 + (size_t)row * FF + (kt + 128) + c4 * 4);
    }
  }
  __builtin_amdgcn_sched_barrier(0);
#pragma unroll
  for (int ks = 0; ks < 2; ++ks) {
    s16x8 af[4], bfr[4];
#pragma unroll
    for (int mi = 0; mi < 4; ++mi) {
      int row = mi * 16 + (lane & 15);
      int byte = row * 128 + (((ks * 64) + (lane >> 4) * 16) ^ ((row & 7) << 4));
      af[mi] = *(const s16x8*)((const char*)Asc + byte);
    }
#pragma unroll
    for (int ni = 0; ni < 4; ++ni) {
      int row = wid * 64 + ni * 16 + (lane & 15);
      int byte = row * 128 + (((ks * 64) + (lane >> 4) * 16) ^ ((row & 7) << 4));
      bfr[ni] = *(const s16x8*)((const char*)Bsc + byte);
    }
#pragma unroll
    for (int mi = 0; mi < 4; ++mi)
#pragma unroll
      for (int ni = 0; ni < 4; ++ni)
        acc[mi][ni] = __builtin_amdgcn_mfma_f32_16x16x32_bf16(af[mi], bfr[ni], acc[mi][ni], 0, 0, 0);
  }
  if (IB) {  // stage A for next tile (regC arrived ~2 phases ago)
#pragma unroll
    for (int i = 0; i < 2; ++i) {
      int idx = i * 512 + t, row = idx >> 4, c4 = idx & 15;
      f32x4 x = regC[i];
      US4 p{f2bf(x.x), f2bf(x.y), f2bf(x.z), f2bf(x.w)};
      int byte = row * 128 + ((c4 * 8) ^ ((row & 7) << 4));
      *(US4*)((char*)Asn + byte) = p;
    }
  }
  asm volatile("s_waitcnt lgkmcnt(0)" ::: "memory");
  __builtin_amdgcn_sched_barrier(0);
  __builtin_amdgcn_s_barrier();
}

__global__ __launch_bounds__(512, 2) void k_gemm1f(
    const float* __restrict__ enc, const unsigned short* __restrict__ Web,
    const float* __restrict__ be, const unsigned short* __restrict__ Waeb,
    const float* __restrict__ bbw, const float* __restrict__ vv,
    unsigned short* __restrict__ eo, float* __restrict__ sp) {
  __shared__ unsigned short smem[73728];  // 144 KB
  const int t = threadIdx.x, lane = t & 63, wid = t >> 6;
  const int m0 = blockIdx.x * 64;
  const float* enc_m0 = enc + (size_t)m0 * FF;
  unsigned short* As0 = smem;
  unsigned short* Bs0 = smem + 8192;
  f32x4 acc[4][4] = {};
  f32x4 areg0[2], areg1[2], aP[2];

  // ---- prologue: A[0]->aP, B[0]->Bs0, A[1]->areg1, cvt A[0]->As0 ----
#pragma unroll
  for (int i = 0; i < 2; ++i) {
    int idx = i * 512 + t, row = idx >> 4, c4 = idx & 15;
    aP[i] = *(const f32x4*)(enc_m0 + (size_t)row * FF + c4 * 4);
  }
  __builtin_amdgcn_sched_barrier(0);
#pragma unroll
  for (int i = 0; i < 8; ++i) {
    int idx = i * 512 + t, row = idx >> 3, c = idx & 7, sc = c ^ (row & 7);
    gload_lds16(Web + (size_t)row * FF + sc * 8, Bs0 + idx * 8);
  }
  __builtin_amdgcn_sched_barrier(0);
#pragma unroll
  for (int i = 0; i < 2; ++i) {
    int idx = i * 512 + t, row = idx >> 4, c4 = idx & 15;
    areg1[i] = *(const f32x4*)(enc_m0 + (size_t)row * FF + 64 + c4 * 4);
  }
  __builtin_amdgcn_sched_barrier(0);
#pragma unroll
  for (int i = 0; i < 2; ++i) {
    int idx = i * 512 + t, row = idx >> 4, c4 = idx & 15;
    f32x4 x = aP[i];
    US4 p{f2bf(x.x), f2bf(x.y), f2bf(x.z), f2bf(x.w)};
    int byte = row * 128 + ((c4 * 8) ^ ((row & 7) << 4));
    *(US4*)((char*)As0 + byte) = p;
  }
  asm volatile("s_waitcnt lgkmcnt(0)" ::: "memory");
  __builtin_amdgcn_sched_barrier(0);
  __builtin_amdgcn_s_barrier();

  // ---- main loop: T = 0..31 ----
  int kt = 0;
#pragma unroll 1
  for (int tt = 0; tt < 15; ++tt) {  // T = 0..29
    gstep<0, true, true, 2>(enc_m0, Web, smem, kt, t, lane, wid, areg1, areg0, acc);
    gstep<1, true, true, 2>(enc_m0, Web, smem, kt + 64, t, lane, wid, areg0, areg1, acc);
    kt += 128;
  }
  gstep<0, true, false, 2>(enc_m0, Web, smem, 1920, t, lane, wid, areg1, areg0, acc);
  gstep<1, false, false, 0>(enc_m0, Web, smem, 1984, t, lane, wid, areg0, areg1, acc);

  // ---- epilogue 1: acc (+be) -> swizzled Cs (aliases Bs1 region) ----
  unsigned short* Cs = smem + 40960;  // [64][512] bf16, byte = r*1024 + ((c*2)^((r&7)<<4))
#pragma unroll
  for (int ni = 0; ni < 4; ++ni) {
    int col = wid * 64 + ni * 16 + (lane & 15);
    float bev = be[col];
#pragma unroll
    for (int mi = 0; mi < 4; ++mi)
#pragma unroll
      for (int j = 0; j < 4; ++j) {
        int row = mi * 16 + (lane >> 4) * 4 + j;
        int byte = row * 1024 + ((col * 2) ^ ((row & 7) << 4));
        *(unsigned short*)((char*)Cs + byte) = f2bf(acc[mi][ni][j] + bev);
      }
  }
  __syncthreads();

  // ---- epilogue 2: coalesced eo store (de-swizzled US8 reads) ----
#pragma unroll
  for (int i = 0; i < 8; ++i) {
    int idx = i * 512 + t, row = idx >> 6, c = idx & 63;
    int byte = row * 1024 + ((c * 16) ^ ((row & 7) << 4));
    *(US8*)(eo + (size_t)(m0 + row) * HH + c * 8) = *(const US8*)((const char*)Cs + byte);
  }

  // ---- epilogue 3: second GEMM  E(64x64 per wave) = eoTile @ Waeb^T ----
  f32x4 acc2[4][4] = {};
#pragma unroll 1
  for (int kt2 = 0; kt2 < HH; kt2 += 64) {
#pragma unroll
    for (int ks = 0; ks < 2; ++ks) {
      int k2 = kt2 + ks * 32 + (lane >> 4) * 8;
      s16x8 af[4], bfr[4];
#pragma unroll
      for (int mi = 0; mi < 4; ++mi) {
        int row = mi * 16 + (lane & 15);
        int byte = row * 1024 + ((k2 * 2) ^ ((row & 7) << 4));
        af[mi] = *(const s16x8*)((const char*)Cs + byte);
      }
#pragma unroll
      for (int ni = 0; ni < 4; ++ni) {
        int nrow = wid * 64 + ni * 16 + (lane & 15);
        bfr[ni] = *(const s16x8*)(Waeb + (size_t)nrow * HH + k2);
      }
#pragma unroll
      for (int mi = 0; mi < 4; ++mi)
#pragma unroll
        for (int ni = 0; ni < 4; ++ni)
          acc2[mi][ni] = __builtin_amdgcn_mfma_f32_16x16x32_bf16(af[mi], bfr[ni], acc2[mi][ni], 0, 0, 0);
    }
  }

  // ---- epilogue 4: scores = sum_n tanh(E + bb) * v ----
  const int b = m0 >> 11;
  float vcol[4], bcol[4];
#pragma unroll
  for (int ni = 0; ni < 4; ++ni) {
    int col = wid * 64 + ni * 16 + (lane & 15);
    vcol[ni] = vv[col];
    bcol[ni] = bbw[b * HH + col];
  }
  float ps[4][4];
#pragma unroll
  for (int mi = 0; mi < 4; ++mi)
#pragma unroll
    for (int j = 0; j < 4; ++j) {
      float s = 0.f;
#pragma unroll
      for (int ni = 0; ni < 4; ++ni)
        s += tanhf(acc2[mi][ni][j] + bcol[ni]) * vcol[ni];
      ps[mi][j] = s;
    }
#pragma unroll
  for (int m = 1; m < 16; m <<= 1)
#pragma unroll
    for (int mi = 0; mi < 4; ++mi)
#pragma unroll
      for (int j = 0; j < 4; ++j) ps[mi][j] += __shfl_xor(ps[mi][j], m);
  float* red = (float*)smem;  // [8][64] floats (As0 region, Cs untouched)
  if ((lane & 15) == 0) {
#pragma unroll
    for (int mi = 0; mi < 4; ++mi)
#pragma unroll
      for (int j = 0; j < 4; ++j)
        red[wid * 64 + mi * 16 + (lane >> 4) * 4 + j] = ps[mi][j];
  }
  __syncthreads();
  if (t < 64) {
    float s = 0.f;
#pragma unroll
    for (int w = 0; w < 8; ++w) s += red[w * 64 + t];
    sp[m0 + t] = s;
  }
}

// ---- softmax over S per batch ----
__global__ void k_softmax(const float* __restrict__ sp, float* __restrict__ attn) {
  const int b = blockIdx.x, t = threadIdx.x, lane = t & 63, wid = t >> 6;
  __shared__ float red[4];
  float vals[8], lmax = -3.0e38f;
#pragma unroll
  for (int i = 0; i < 8; ++i) {
    float x = sp[b * SS + t + i * 256];
    vals[i] = x;
    lmax = fmaxf(lmax, x);
  }
#pragma unroll
  for (int m = 32; m; m >>= 1) lmax = fmaxf(lmax, __shfl_xor(lmax, m));
  if (lane == 0) red[wid] = lmax;
  __syncthreads();
  lmax = fmaxf(fmaxf(red[0], red[1]), fmaxf(red[2], red[3]));
  __syncthreads();
  float lsum = 0.f;
#pragma unroll
  for (int i = 0; i < 8; ++i) {
    vals[i] = __expf(vals[i] - lmax);
    lsum += vals[i];
  }
#pragma unroll
  for (int m = 32; m; m >>= 1) lsum += __shfl_xor(lsum, m);
  if (lane == 0) red[wid] = lsum;
  __syncthreads();
  float inv = 1.0f / (red[0] + red[1] + red[2] + red[3]);
#pragma unroll
  for (int i = 0; i < 8; ++i) attn[b * SS + t + i * 256] = vals[i] * inv;
}

// ---- context stage 1: 128-row s-chunks, 256 blocks ----
__global__ __launch_bounds__(512) void k_ctx1(const unsigned short* __restrict__ eo,
                                              const float* __restrict__ attn,
                                              float* __restrict__ cp) {
  __shared__ float red[8][512];
  const int b = blockIdx.x >> 4, ch = blockIdx.x & 15, t = threadIdx.x;
  const int tg = t & 63, sg = t >> 6;
  const float* aw = attn + b * SS + ch * 128;
  float acc[8] = {};
#pragma unroll 4
  for (int i = 0; i < 16; ++i) {
    int s = sg + i * 8;
    float w = aw[s];
    US8 vv8 = *(const US8*)(eo + (size_t)(b * SS + ch * 128 + s) * HH + tg * 8);
#pragma unroll
    for (int j = 0; j < 8; ++j) acc[j] += w * bf2f(vv8.s[j]);
  }
#pragma unroll
  for (int j = 0; j < 8; ++j) red[sg][tg * 8 + j] = acc[j];
  __syncthreads();
  float a = 0.f;
#pragma unroll
  for (int g = 0; g < 8; ++g) a += red[g][t];
  cp[(size_t)blockIdx.x * HH + t] = a;
}

// ---- context stage 2 ----
__global__ void k_ctx2(const float* __restrict__ cp, float* __restrict__ ctx) {
  const int b = blockIdx.x, h = threadIdx.x;
  float a = 0.f;
#pragma unroll
  for (int c = 0; c < 16; ++c) a += cp[(size_t)(b * 16 + c) * HH + h];
  ctx[b * HH + h] = a;
}

extern "C" void kernel_launch(void* const* d_in, const int* in_sizes, int n_in,
                              void* d_out, int out_size, void* d_ws, size_t ws_size,
                              hipStream_t stream) {
  (void)in_sizes; (void)n_in; (void)out_size; (void)ws_size;
  const float* hidden = (const float*)d_in[0];
  const float* enc    = (const float*)d_in[1];
  const float* We     = (const float*)d_in[2];
  const float* be     = (const float*)d_in[3];
  const float* Wh     = (const float*)d_in[4];
  const float* bh     = (const float*)d_in[5];
  const float* Wa     = (const float*)d_in[6];
  const float* ba     = (const float*)d_in[7];
  const float* v      = (const float*)d_in[8];

  float* out  = (float*)d_out;
  float* ctx  = out;            // 16*512
  float* attn = out + BB * HH;  // 16*2048

  char* ws = (char*)d_ws;
  unsigned short* Web  = (unsigned short*)ws;  ws += (size_t)HH * FF * 2;     // 2 MB
  unsigned short* Waeb = (unsigned short*)ws;  ws += (size_t)HH * HH * 2;     // 512 KB
  float* h_ws  = (float*)ws;                   ws += (size_t)BB * HH * 4;     // 32 KB
  float* bb_ws = (float*)ws;                   ws += (size_t)BB * HH * 4;     // 32 KB
  unsigned short* eo = (unsigned short*)ws;    ws += (size_t)MM * HH * 2;     // 32 MB
  float* sp = (float*)ws;                      ws += (size_t)MM * 4;          // 128 KB
  float* cp = (float*)ws;                      ws += (size_t)BB * 16 * HH * 4;// 512 KB

  k_conv<<<1280, 256, 0, stream>>>(We, Wa, Web, Waeb);
  k_h<<<2048, 256, 0, stream>>>(hidden, Wh, bh, h_ws);
  k_bb<<<2048, 256, 0, stream>>>(h_ws, Wa, ba, bb_ws);
  k_gemm1f<<<512, 512, 0, stream>>>(enc, Web, be, Waeb, bb_ws, v, eo, sp);
  k_softmax<<<16, 256, 0, stream>>>(sp, attn);
  k_ctx1<<<256, 512, 0, stream>>>(eo, attn, cp);
  k_ctx2<<<16, 512, 0, stream>>>(cp, ctx);
}

// Round 5
// 168.755 us; speedup vs baseline: 1.1098x; 1.1098x over previous
//
#include <hip/hip_runtime.h>
#include <math.h>

#define HH 512
#define FF 2048
#define BB 16
#define SS 2048
#define MM 32768  // BB*SS

using f32x4 = __attribute__((ext_vector_type(4))) float;
using s16x8 = __attribute__((ext_vector_type(8))) short;

struct __align__(8)  US4 { unsigned short x, y, z, w; };
struct __align__(16) US8 { unsigned short s[8]; };

__device__ __forceinline__ unsigned short f2bf(float f) {
  unsigned int u = __builtin_bit_cast(unsigned int, f);
  u += 0x7fffu + ((u >> 16) & 1u);
  return (unsigned short)(u >> 16);
}
__device__ __forceinline__ float bf2f(unsigned short u) {
  unsigned int x = ((unsigned int)u) << 16;
  return __builtin_bit_cast(float, x);
}
__device__ __forceinline__ void gload_lds16(const void* g, void* l) {
  __builtin_amdgcn_global_load_lds(
      (const __attribute__((address_space(1))) unsigned int*)g,
      (__attribute__((address_space(3))) unsigned int*)l, 16, 0, 0);
}

// ---- weight conversions (merged) ----
__global__ void k_conv(const float* __restrict__ We, const float* __restrict__ Wa,
                       unsigned short* __restrict__ OWe, unsigned short* __restrict__ OWa) {
  int bid = blockIdx.x, t = threadIdx.x;
  if (bid < 1024) {
    int idx = bid * 256 + t;  // < 262144
    f32x4 x = *(const f32x4*)(We + (size_t)idx * 4);
    US4 p{f2bf(x.x), f2bf(x.y), f2bf(x.z), f2bf(x.w)};
    *(US4*)(OWe + (size_t)idx * 4) = p;
  } else {
    int idx = (bid - 1024) * 256 + t;  // < 65536
    int k = idx >> 7, h4 = idx & 127;
    f32x4 x = *(const f32x4*)(Wa + (size_t)k * 1024 + 512 + h4 * 4);
    US4 p{f2bf(x.x), f2bf(x.y), f2bf(x.z), f2bf(x.w)};
    *(US4*)(OWa + (size_t)idx * 4) = p;
  }
}

// ---- h = hidden[-1] @ Wh.T + bh : one wave per output (b,j) ----
__global__ void k_h(const float* __restrict__ hidden, const float* __restrict__ Wh,
                    const float* __restrict__ bh, float* __restrict__ h_ws) {
  int t = threadIdx.x, lane = t & 63, wid = t >> 6;
  int out = blockIdx.x * 4 + wid;  // < 8192
  int b = out >> 9, j = out & 511;
  const float* hr = hidden + (1) * BB * FF + b * FF;  // hidden[-1]
  const float* wr = Wh + (size_t)j * FF;
  float a = 0.f;
#pragma unroll
  for (int i = 0; i < 8; ++i) {
    int o = i * 256 + lane * 4;
    f32x4 x = *(const f32x4*)(hr + o);
    f32x4 y = *(const f32x4*)(wr + o);
    a += x.x * y.x + x.y * y.y + x.z * y.z + x.w * y.w;
  }
#pragma unroll
  for (int m = 32; m; m >>= 1) a += __shfl_xor(a, m);
  if (lane == 0) h_ws[out] = a + bh[j];
}

// ---- bb[b][k] = ba[k] + h[b] . Wa[k, 0:512] ----
__global__ void k_bb(const float* __restrict__ h_ws, const float* __restrict__ Wa,
                     const float* __restrict__ ba, float* __restrict__ bb_ws) {
  int t = threadIdx.x, lane = t & 63, wid = t >> 6;
  int out = blockIdx.x * 4 + wid;  // < 8192
  int b = out >> 9, k = out & 511;
  const float* hr = h_ws + b * HH;
  const float* wa = Wa + (size_t)k * 1024;
  float a = 0.f;
#pragma unroll
  for (int i = 0; i < 2; ++i) {
    int o = i * 256 + lane * 4;
    f32x4 x = *(const f32x4*)(hr + o);
    f32x4 y = *(const f32x4*)(wa + o);
    a += x.x * y.x + x.y * y.y + x.z * y.z + x.w * y.w;
  }
#pragma unroll
  for (int m = 32; m; m >>= 1) a += __shfl_xor(a, m);
  if (lane == 0) bb_ws[out] = a + ba[k];
}

// ============== fused GEMM1 + GEMM2 + scores (R3 main-loop structure) ==========
// Block: M=64 x N=512 (full N, enc read once). 512 thr / 8 waves, BK=64.
// SINGLE-buffered LDS 72KB (As 8KB + Bs 64KB) => 2 blocks/CU (m114 overlap).
// Compiler-managed barriers (__syncthreads). XOR-swizzle both sides (rule 21).
// Epilogue: acc(+be) -> swizzled Cs (aliases Bs @ +8KB) -> eo store + GEMM2
// (E = eoTile @ Waeb^T, B-frags from L2) -> tanh+v-dot -> scores sp.
__global__ __launch_bounds__(512, 4) void k_gemm1f(
    const float* __restrict__ enc, const unsigned short* __restrict__ Web,
    const float* __restrict__ be, const unsigned short* __restrict__ Waeb,
    const float* __restrict__ bbw, const float* __restrict__ vv,
    unsigned short* __restrict__ eo, float* __restrict__ sp) {
  __shared__ unsigned short smem[36864];  // 72 KB
  unsigned short* As = smem;              // [64][64] swizzled
  unsigned short* Bs = smem + 4096;       // [512][64] swizzled
  const int t = threadIdx.x, lane = t & 63, wid = t >> 6;
  const int m0 = blockIdx.x * 64;
  const float* enc_m0 = enc + (size_t)m0 * FF;
  f32x4 acc[4][4] = {};

  f32x4 areg[2];
#pragma unroll
  for (int i = 0; i < 2; ++i) {
    int idx = i * 512 + t, row = idx >> 4, c4 = idx & 15;
    areg[i] = *(const f32x4*)(enc_m0 + (size_t)row * FF + c4 * 4);
  }

#pragma unroll 1
  for (int kt = 0; kt < FF; kt += 64) {
    // B tile: rows 0..511 of Web, pre-swizzled source chunk -> linear LDS
#pragma unroll
    for (int i = 0; i < 8; ++i) {
      int idx = i * 512 + t, row = idx >> 3, c = idx & 7, sc = c ^ (row & 7);
      gload_lds16(Web + (size_t)row * FF + kt + sc * 8, Bs + idx * 8);
    }
    // A tile: cvt prefetched regs -> swizzled ds_write
#pragma unroll
    for (int i = 0; i < 2; ++i) {
      int idx = i * 512 + t, row = idx >> 4, c4 = idx & 15;
      f32x4 x = areg[i];
      US4 p{f2bf(x.x), f2bf(x.y), f2bf(x.z), f2bf(x.w)};
      int byte = row * 128 + ((c4 * 8) ^ ((row & 7) << 4));
      *(US4*)((char*)As + byte) = p;
    }
    // prefetch next A (lands during this phase's compute)
    {
      int ktn = (kt + 64 < FF) ? kt + 64 : 0;
#pragma unroll
      for (int i = 0; i < 2; ++i) {
        int idx = i * 512 + t, row = idx >> 4, c4 = idx & 15;
        areg[i] = *(const f32x4*)(enc_m0 + (size_t)row * FF + ktn + c4 * 4);
      }
    }
    __syncthreads();
#pragma unroll
    for (int ks = 0; ks < 2; ++ks) {
      s16x8 af[4], bfr[4];
#pragma unroll
      for (int mi = 0; mi < 4; ++mi) {
        int row = mi * 16 + (lane & 15);
        int byte = row * 128 + (((ks * 64) + (lane >> 4) * 16) ^ ((row & 7) << 4));
        af[mi] = *(const s16x8*)((const char*)As + byte);
      }
#pragma unroll
      for (int ni = 0; ni < 4; ++ni) {
        int row = wid * 64 + ni * 16 + (lane & 15);
        int byte = row * 128 + (((ks * 64) + (lane >> 4) * 16) ^ ((row & 7) << 4));
        bfr[ni] = *(const s16x8*)((const char*)Bs + byte);
      }
#pragma unroll
      for (int mi = 0; mi < 4; ++mi)
#pragma unroll
        for (int ni = 0; ni < 4; ++ni)
          acc[mi][ni] = __builtin_amdgcn_mfma_f32_16x16x32_bf16(af[mi], bfr[ni], acc[mi][ni], 0, 0, 0);
    }
    __syncthreads();  // all As/Bs reads done before next stage overwrites
  }

  // ---- epilogue 1: acc (+be) -> swizzled Cs (Bs region, 64KB) ----
  unsigned short* Cs = smem + 4096;  // [64][512] bf16, byte = r*1024 + ((c*2)^((r&7)<<4))
#pragma unroll
  for (int ni = 0; ni < 4; ++ni) {
    int col = wid * 64 + ni * 16 + (lane & 15);
    float bev = be[col];
#pragma unroll
    for (int mi = 0; mi < 4; ++mi)
#pragma unroll
      for (int j = 0; j < 4; ++j) {
        int row = mi * 16 + (lane >> 4) * 4 + j;
        int byte = row * 1024 + ((col * 2) ^ ((row & 7) << 4));
        *(unsigned short*)((char*)Cs + byte) = f2bf(acc[mi][ni][j] + bev);
      }
  }
  __syncthreads();

  // ---- epilogue 2: coalesced eo store (de-swizzled US8 reads) ----
#pragma unroll
  for (int i = 0; i < 8; ++i) {
    int idx = i * 512 + t, row = idx >> 6, c = idx & 63;
    int byte = row * 1024 + ((c * 16) ^ ((row & 7) << 4));
    *(US8*)(eo + (size_t)(m0 + row) * HH + c * 8) = *(const US8*)((const char*)Cs + byte);
  }

  // ---- epilogue 3: GEMM2  E(64x64 per wave) = eoTile @ Waeb^T ----
  f32x4 acc2[4][4] = {};
#pragma unroll 1
  for (int kt2 = 0; kt2 < HH; kt2 += 64) {
#pragma unroll
    for (int ks = 0; ks < 2; ++ks) {
      int k2 = kt2 + ks * 32 + (lane >> 4) * 8;
      s16x8 af[4], bfr[4];
#pragma unroll
      for (int mi = 0; mi < 4; ++mi) {
        int row = mi * 16 + (lane & 15);
        int byte = row * 1024 + ((k2 * 2) ^ ((row & 7) << 4));
        af[mi] = *(const s16x8*)((const char*)Cs + byte);
      }
#pragma unroll
      for (int ni = 0; ni < 4; ++ni) {
        int nrow = wid * 64 + ni * 16 + (lane & 15);
        bfr[ni] = *(const s16x8*)(Waeb + (size_t)nrow * HH + k2);
      }
#pragma unroll
      for (int mi = 0; mi < 4; ++mi)
#pragma unroll
        for (int ni = 0; ni < 4; ++ni)
          acc2[mi][ni] = __builtin_amdgcn_mfma_f32_16x16x32_bf16(af[mi], bfr[ni], acc2[mi][ni], 0, 0, 0);
    }
  }

  // ---- epilogue 4: scores = sum_n tanh(E + bb) * v  (red @ smem+0, no Cs overlap) ----
  const int b = m0 >> 11;
  float vcol[4], bcol[4];
#pragma unroll
  for (int ni = 0; ni < 4; ++ni) {
    int col = wid * 64 + ni * 16 + (lane & 15);
    vcol[ni] = vv[col];
    bcol[ni] = bbw[b * HH + col];
  }
  float ps[4][4];
#pragma unroll
  for (int mi = 0; mi < 4; ++mi)
#pragma unroll
    for (int j = 0; j < 4; ++j) {
      float s = 0.f;
#pragma unroll
      for (int ni = 0; ni < 4; ++ni)
        s += tanhf(acc2[mi][ni][j] + bcol[ni]) * vcol[ni];
      ps[mi][j] = s;
    }
#pragma unroll
  for (int m = 1; m < 16; m <<= 1)
#pragma unroll
    for (int mi = 0; mi < 4; ++mi)
#pragma unroll
      for (int j = 0; j < 4; ++j) ps[mi][j] += __shfl_xor(ps[mi][j], m);
  float* red = (float*)smem;  // [8][64] floats = 2KB (As region; Cs untouched)
  if ((lane & 15) == 0) {
#pragma unroll
    for (int mi = 0; mi < 4; ++mi)
#pragma unroll
      for (int j = 0; j < 4; ++j)
        red[wid * 64 + mi * 16 + (lane >> 4) * 4 + j] = ps[mi][j];
  }
  __syncthreads();
  if (t < 64) {
    float s = 0.f;
#pragma unroll
    for (int w = 0; w < 8; ++w) s += red[w * 64 + t];
    sp[m0 + t] = s;
  }
}

// ---- softmax over S per batch ----
__global__ void k_softmax(const float* __restrict__ sp, float* __restrict__ attn) {
  const int b = blockIdx.x, t = threadIdx.x, lane = t & 63, wid = t >> 6;
  __shared__ float red[4];
  float vals[8], lmax = -3.0e38f;
#pragma unroll
  for (int i = 0; i < 8; ++i) {
    float x = sp[b * SS + t + i * 256];
    vals[i] = x;
    lmax = fmaxf(lmax, x);
  }
#pragma unroll
  for (int m = 32; m; m >>= 1) lmax = fmaxf(lmax, __shfl_xor(lmax, m));
  if (lane == 0) red[wid] = lmax;
  __syncthreads();
  lmax = fmaxf(fmaxf(red[0], red[1]), fmaxf(red[2], red[3]));
  __syncthreads();
  float lsum = 0.f;
#pragma unroll
  for (int i = 0; i < 8; ++i) {
    vals[i] = __expf(vals[i] - lmax);
    lsum += vals[i];
  }
#pragma unroll
  for (int m = 32; m; m >>= 1) lsum += __shfl_xor(lsum, m);
  if (lane == 0) red[wid] = lsum;
  __syncthreads();
  float inv = 1.0f / (red[0] + red[1] + red[2] + red[3]);
#pragma unroll
  for (int i = 0; i < 8; ++i) attn[b * SS + t + i * 256] = vals[i] * inv;
}

// ---- context stage 1: 128-row s-chunks, 256 blocks ----
__global__ __launch_bounds__(512) void k_ctx1(const unsigned short* __restrict__ eo,
                                              const float* __restrict__ attn,
                                              float* __restrict__ cp) {
  __shared__ float red[8][512];
  const int b = blockIdx.x >> 4, ch = blockIdx.x & 15, t = threadIdx.x;
  const int tg = t & 63, sg = t >> 6;
  const float* aw = attn + b * SS + ch * 128;
  float acc[8] = {};
#pragma unroll 4
  for (int i = 0; i < 16; ++i) {
    int s = sg + i * 8;
    float w = aw[s];
    US8 vv8 = *(const US8*)(eo + (size_t)(b * SS + ch * 128 + s) * HH + tg * 8);
#pragma unroll
    for (int j = 0; j < 8; ++j) acc[j] += w * bf2f(vv8.s[j]);
  }
#pragma unroll
  for (int j = 0; j < 8; ++j) red[sg][tg * 8 + j] = acc[j];
  __syncthreads();
  float a = 0.f;
#pragma unroll
  for (int g = 0; g < 8; ++g) a += red[g][t];
  cp[(size_t)blockIdx.x * HH + t] = a;
}

// ---- context stage 2 ----
__global__ void k_ctx2(const float* __restrict__ cp, float* __restrict__ ctx) {
  const int b = blockIdx.x, h = threadIdx.x;
  float a = 0.f;
#pragma unroll
  for (int c = 0; c < 16; ++c) a += cp[(size_t)(b * 16 + c) * HH + h];
  ctx[b * HH + h] = a;
}

extern "C" void kernel_launch(void* const* d_in, const int* in_sizes, int n_in,
                              void* d_out, int out_size, void* d_ws, size_t ws_size,
                              hipStream_t stream) {
  (void)in_sizes; (void)n_in; (void)out_size; (void)ws_size;
  const float* hidden = (const float*)d_in[0];
  const float* enc    = (const float*)d_in[1];
  const float* We     = (const float*)d_in[2];
  const float* be     = (const float*)d_in[3];
  const float* Wh     = (const float*)d_in[4];
  const float* bh     = (const float*)d_in[5];
  const float* Wa     = (const float*)d_in[6];
  const float* ba     = (const float*)d_in[7];
  const float* v      = (const float*)d_in[8];

  float* out  = (float*)d_out;
  float* ctx  = out;            // 16*512
  float* attn = out + BB * HH;  // 16*2048

  char* ws = (char*)d_ws;
  unsigned short* Web  = (unsigned short*)ws;  ws += (size_t)HH * FF * 2;     // 2 MB
  unsigned short* Waeb = (unsigned short*)ws;  ws += (size_t)HH * HH * 2;     // 512 KB
  float* h_ws  = (float*)ws;                   ws += (size_t)BB * HH * 4;     // 32 KB
  float* bb_ws = (float*)ws;                   ws += (size_t)BB * HH * 4;     // 32 KB
  unsigned short* eo = (unsigned short*)ws;    ws += (size_t)MM * HH * 2;     // 32 MB
  float* sp = (float*)ws;                      ws += (size_t)MM * 4;          // 128 KB
  float* cp = (float*)ws;                      ws += (size_t)BB * 16 * HH * 4;// 512 KB

  k_conv<<<1280, 256, 0, stream>>>(We, Wa, Web, Waeb);
  k_h<<<2048, 256, 0, stream>>>(hidden, Wh, bh, h_ws);
  k_bb<<<2048, 256, 0, stream>>>(h_ws, Wa, ba, bb_ws);
  k_gemm1f<<<512, 512, 0, stream>>>(enc, Web, be, Waeb, bb_ws, v, eo, sp);
  k_softmax<<<16, 256, 0, stream>>>(sp, attn);
  k_ctx1<<<256, 512, 0, stream>>>(eo, attn, cp);
  k_ctx2<<<16, 512, 0, stream>>>(cp, ctx);
}